// Round 16
// baseline (466.088 us; speedup 1.0000x reference)
//
#include <hip/hip_runtime.h>
#include <math.h>

// Problem constants
#define BATCH 128
#define TENC  64
#define NSTEP 63

// Workspace layout (FLOAT offsets)
#define OFF_WA1ET  0         // [256 k][256 j] f32 : W_a1[j][512+k]  (for enc_proj)
#define OFF_EPT    65536     // [128 b][256 j][64 t] f32
#define OFF_PKH    2162688   // fp16 region (half offsets within):
                             //   PK1r: [0,131072) = [ks<2][it<32][j<256][m<8]
                             //         idx256=it*8+m; k = idx256<128 ? ks*128+idx256
                             //                                       : 256+ks*128+(idx256-128)
                             //         = Wa1[j][k]  (ks = k-slice set)
                             //   PKG:  [131072,393216) = [h1<2][kk<16][kh<2][q'<512][m<8]
                             //         = Whh[q][k], q=(q'>>7)*256+h1*128+(q'&127), k=kh*128+kk*8+m
#define OFF_HX     2359296   // [2 p][128 b][2 half][128] u32 packed state {h:f16 lo, c:f16 hi}
#define OFF_FLAGS  2424832   // [128 b][2 half][2] uint (monotonic; [0]=state)

// LDS flag ids
#define SF 0   // peer state in LDS   (2 posts/step, s>=1)
#define AF 1   // red1 ready          (8 posts/step)
#define CF 2   // red2 ready          (8 posts/step)
#define GF 3   // g2 ready            (8 posts/step)
#define UF 4   // own state updated   (2 posts/step)
#define HF 5   // HX posts drained    (2 posts/step)

typedef __attribute__((ext_vector_type(8))) _Float16 h8_t;
typedef __attribute__((ext_vector_type(2))) _Float16 h2_t;

#if defined(__has_builtin)
#if __has_builtin(__builtin_amdgcn_fdot2)
#define FDOT2(a, b, c) __builtin_amdgcn_fdot2((a), (b), (c), false)
#endif
#endif
#ifndef FDOT2
#define FDOT2(a, b, c) ((c) + (float)(a)[0] * (float)(b)[0] + (float)(a)[1] * (float)(b)[1])
#endif

__device__ __forceinline__ h2_t h2of(h8_t v, int i) {
    h2_t r = {v[2 * i], v[2 * i + 1]};
    return r;
}
__device__ __forceinline__ float ftanh(float x) {
    x = fminf(15.f, fmaxf(-15.f, x));
    float e = __expf(2.f * x);
    return (e - 1.f) * __builtin_amdgcn_rcpf(e + 1.f);
}
__device__ __forceinline__ float fsig(float x) {
    return __builtin_amdgcn_rcpf(1.f + __expf(-x));
}
__device__ __forceinline__ unsigned pack_hc(float h, float c) {
    unsigned short hu = __builtin_bit_cast(unsigned short, (_Float16)h);
    unsigned short cu = __builtin_bit_cast(unsigned short, (_Float16)c);
    return (unsigned)hu | ((unsigned)cu << 16);
}
#define FENCE() asm volatile("" ::: "memory")
#define LGKM0() asm volatile("s_waitcnt lgkmcnt(0)" ::: "memory")

// ---------------------------------------------------------------------------
// Pre-kernel A: pack weights (fp16 stream-ordered) + WA1ET (f32)
// ---------------------------------------------------------------------------
__global__ void pack_weights(const float* __restrict__ Wa1,
                             const float* __restrict__ Whh,
                             float* __restrict__ ws) {
    int idx = blockIdx.x * blockDim.x + threadIdx.x;
    _Float16* PKH = (_Float16*)(ws + OFF_PKH);
    if (idx < 131072) {
        // PK1r: flat = ((ks*32+it)*256 + j)*8 + m
        int m = idx & 7, j = (idx >> 3) & 255, it = (idx >> 11) & 31, ks = idx >> 16;
        int idx256 = it * 8 + m;
        int k = (idx256 < 128) ? ks * 128 + idx256
                               : 256 + ks * 128 + (idx256 - 128);
        PKH[idx] = (_Float16)Wa1[j * 768 + k];
    } else if (idx < 393216) {
        int n = idx - 131072;
        int m = n & 7, qp = (n >> 3) & 511, kh = (n >> 12) & 1, kk = (n >> 13) & 15, h1 = n >> 17;
        int q = ((qp >> 7) << 8) + h1 * 128 + (qp & 127);
        int k = kh * 128 + kk * 8 + m;
        PKH[131072 + n] = (_Float16)Whh[q * 256 + k];
    } else if (idx < 458752) {
        int n = idx - 393216;
        int k = n >> 8, j = n & 255;
        ws[OFF_WA1ET + n] = Wa1[j * 768 + 512 + k];
    }
}

// Pre-kernel A2: zero the exchange flags
__global__ void zero_flags(float* __restrict__ ws) {
    unsigned* f = (unsigned*)(ws + OFF_FLAGS);
    f[threadIdx.x] = 0u;   // 512 = [128][2][2]
}

// ---------------------------------------------------------------------------
// Pre-kernel B: EPT[b][j][t] = b_a1[j] + sum_k enc[b][t][k] * W_a1[j][512+k]
// ---------------------------------------------------------------------------
__global__ void enc_proj_kernel(const float* __restrict__ enc,
                                const float* __restrict__ ba1,
                                float* __restrict__ ws) {
    __shared__ float smem[8448];
    const int b  = blockIdx.x >> 1;
    const int th = blockIdx.x & 1;
    const int t0 = th * 32;
    const int tid = threadIdx.x;

    const float* encb = enc + (b * TENC + t0) * 256;
    for (int c = 0; c < 32; ++c) smem[c * 256 + tid] = encb[c * 256 + tid];
    __syncthreads();

    const int w = tid >> 6, l = tid & 63;
    float acc[8][4];
    #pragma unroll
    for (int a = 0; a < 8; ++a)
        #pragma unroll
        for (int c = 0; c < 4; ++c) acc[a][c] = 0.f;

    const float4* WT = (const float4*)(ws + OFF_WA1ET);
    for (int k = 0; k < 256; ++k) {
        float4 wv = WT[k * 64 + l];
        #pragma unroll
        for (int tt = 0; tt < 8; ++tt) {
            float e = smem[(w * 8 + tt) * 256 + k];
            acc[tt][0] += e * wv.x; acc[tt][1] += e * wv.y;
            acc[tt][2] += e * wv.z; acc[tt][3] += e * wv.w;
        }
    }
    float4 bb = ((const float4*)ba1)[l];
    __syncthreads();
    #pragma unroll
    for (int tt = 0; tt < 8; ++tt) {
        smem[(4 * l + 0) * 33 + w * 8 + tt] = acc[tt][0] + bb.x;
        smem[(4 * l + 1) * 33 + w * 8 + tt] = acc[tt][1] + bb.y;
        smem[(4 * l + 2) * 33 + w * 8 + tt] = acc[tt][2] + bb.z;
        smem[(4 * l + 3) * 33 + w * 8 + tt] = acc[tt][3] + bb.w;
    }
    __syncthreads();
    float* EPT = ws + OFF_EPT + b * 16384;
    for (int c = 0; c < 32; ++c) {
        int i = c * 256 + tid;
        int j = i >> 5, t5 = i & 31;
        EPT[j * 64 + t0 + t5] = smem[j * 33 + t5];
    }
}

// ---------------------------------------------------------------------------
// Main kernel: 256 WGs = 2 per batch; WG h1 owns state slice [h1*128,+128).
// REDUNDANT ATTENTION: each WG computes full z / tanh / softmax / ytil
// (bit-identical across the pair); only the gate GEMV + state update is
// split. Single cross-WG exchange per step: packed state (double-buffered
// by step parity). Wave split: A = waves 0-7 (P1 + attention + update),
// B = waves 8-15 (state ingest + full-k gate GEMV). No in-loop barriers;
// monotonic LDS flag counters sequence everything (WAR audit in notes).
// ---------------------------------------------------------------------------
__global__ __launch_bounds__(1024, 4) void decoder_main(
    const float* __restrict__ enc, const float* __restrict__ yhist,
    const float* __restrict__ Wa2,
    const float* __restrict__ Wfc, const float* __restrict__ bfc,
    const float* __restrict__ wih, const float* __restrict__ bih,
    const float* __restrict__ bhh,
    const float* __restrict__ Wff, const float* __restrict__ bff,
    float* __restrict__ ws, float* __restrict__ out) {

    __shared__ float hc[512];        // f32 state: h=[0,256), c=[256,512)
    __shared__ _Float16 hcf16[512] __attribute__((aligned(16)));
    __shared__ float red1[512];      // P1 partials [kc<2][j<256]
    __shared__ float red2[512];      // score partials [w<8][t<64]
    __shared__ float g2[512];        // complete gate dots [q'<512]
    __shared__ float attnw[64];
    __shared__ float encw[64];
    __shared__ float wa2s[256];
    __shared__ float ys[64];
    __shared__ unsigned fl[8];
    __shared__ h8_t  wc[7168] __attribute__((aligned(16)));      // 112 KB: W_a1 peer-k it<28
    __shared__ _Float16 epl[16384] __attribute__((aligned(16))); // EPT[b] f16 [256 j][64 t]

    const int bid  = blockIdx.x;
    const int b    = bid & 127;
    const int h1   = bid >> 7;
    const int tid  = threadIdx.x;

    const _Float16* PKH = (const _Float16*)(ws + OFF_PKH);
    const float* EPTb = ws + OFF_EPT + b * 16384;
    const float* encb = enc + b * 16384;

    // ---- prologue ----
    if (tid < 512) { hc[tid] = 0.f; hcf16[tid] = (_Float16)0.f; }
    if (tid < 256) wa2s[tid] = Wa2[tid];
    if (tid < NSTEP) ys[tid] = yhist[b * NSTEP + tid];
    if (tid < 8) fl[tid] = 0u;
    {   // encw partials into wc scratch (before wc is loaded)
        float* scr = (float*)wc;
        const int t = tid >> 4, cch = tid & 15;
        float p = 0.f;
        #pragma unroll
        for (int i = 0; i < 16; ++i)
            p += encb[t * 256 + cch * 16 + i] * Wfc[cch * 16 + i];
        scr[t * 16 + cch] = p;
    }
    __syncthreads();
    if (tid < 64) {
        float s = 0.f;
        #pragma unroll
        for (int c = 0; c < 16; ++c) s += ((float*)wc)[tid * 16 + c];
        encw[tid] = s;
    }
    __syncthreads();
    // epl f16 staging
    #pragma unroll
    for (int i = 0; i < 16; ++i)
        epl[i * 1024 + tid] = (_Float16)EPTb[i * 1024 + tid];
    // W_a1 peer-k LDS cache (it < 28 of 32)
    const h8_t* W1pBase = (const h8_t*)PKH + (1 - h1) * 8192;
    #pragma unroll
    for (int i = 0; i < 7; ++i) wc[i * 1024 + tid] = W1pBase[i * 1024 + tid];
    const float bfc0  = bfc[0];
    const float wfc_y = Wfc[256];
    float wii = 0.f, wif = 0.f, wig = 0.f, wio = 0.f;
    float bsi = 0.f, bsf = 0.f, bsg = 0.f, bso = 0.f;
    if (tid < 128) {
        const int q0 = h1 * 128 + tid;
        wii = wih[q0];       bsi = bih[q0]       + bhh[q0];
        wif = wih[256 + q0]; bsf = bih[256 + q0] + bhh[256 + q0];
        wig = wih[512 + q0]; bsg = bih[512 + q0] + bhh[512 + q0];
        wio = wih[768 + q0]; bso = bih[768 + q0] + bhh[768 + q0];
    }
    __syncthreads();

    // A mappings: tid<256 = own-k P1 (stream); tid in [256,512) = peer-k P1
    const int j8 = tid & 255;
    const h8_t* W1o = (const h8_t*)PKH + h1 * 8192 + j8;       // own-k, stream
    const h8_t* W1p = W1pBase + j8;                            // peer-k tail
    // B mapping: q' = tid - 512, full 256-k dot
    const h8_t* PKGown = (const h8_t*)(PKH + 131072) + h1 * 16384;
    const h8_t* W4 = PKGown + (tid - 512);

    // exchange buffers / flags
    unsigned* HXbase = (unsigned*)(ws + OFF_HX);
    unsigned* FLGown  = (unsigned*)(ws + OFF_FLAGS) + (b * 2 + h1) * 2;
    unsigned* FLGpeer = (unsigned*)(ws + OFF_FLAGS) + (b * 2 + (1 - h1)) * 2;

    for (int step = 0; step < NSTEP; ++step) {
        const unsigned tgt = (unsigned)(step + 1);
        if (tid < 512) {
            // ===================== GROUP A =====================
            float a0 = 0.f, a1 = 0.f;
            if (tid < 256) {
                // waves 0-3: own-k full P1 column (128 KB stream total)
                while (atomicAdd(&fl[UF], 0u) < 2u * (unsigned)step)
                    __builtin_amdgcn_s_sleep(1);
                FENCE();
                const _Float16* hv_h = hcf16 + h1 * 128;
                const _Float16* hv_c = hcf16 + 256 + h1 * 128;
                #pragma unroll 4
                for (int it = 0; it < 16; ++it) {
                    h8_t w  = W1o[it * 256];
                    h8_t hv = *(const h8_t*)(hv_h + it * 8);
                    a0 = FDOT2(h2of(w, 0), h2of(hv, 0), a0);
                    a1 = FDOT2(h2of(w, 1), h2of(hv, 1), a1);
                    a0 = FDOT2(h2of(w, 2), h2of(hv, 2), a0);
                    a1 = FDOT2(h2of(w, 3), h2of(hv, 3), a1);
                }
                #pragma unroll 4
                for (int it = 0; it < 16; ++it) {
                    h8_t w  = W1o[(16 + it) * 256];
                    h8_t hv = *(const h8_t*)(hv_c + it * 8);
                    a0 = FDOT2(h2of(w, 0), h2of(hv, 0), a0);
                    a1 = FDOT2(h2of(w, 1), h2of(hv, 1), a1);
                    a0 = FDOT2(h2of(w, 2), h2of(hv, 2), a0);
                    a1 = FDOT2(h2of(w, 3), h2of(hv, 3), a1);
                }
                red1[j8] = a0 + a1;
            } else {
                // waves 4-7: peer-k full P1 column (LDS-cached + 16 KB tail)
                while (atomicAdd(&fl[SF], 0u) < 2u * (unsigned)step)
                    __builtin_amdgcn_s_sleep(1);
                FENCE();
                const _Float16* hv_h = hcf16 + (1 - h1) * 128;
                const _Float16* hv_c = hcf16 + 256 + (1 - h1) * 128;
                #pragma unroll 4
                for (int it = 0; it < 16; ++it) {
                    h8_t w  = wc[it * 256 + j8];
                    h8_t hv = *(const h8_t*)(hv_h + it * 8);
                    a0 = FDOT2(h2of(w, 0), h2of(hv, 0), a0);
                    a1 = FDOT2(h2of(w, 1), h2of(hv, 1), a1);
                    a0 = FDOT2(h2of(w, 2), h2of(hv, 2), a0);
                    a1 = FDOT2(h2of(w, 3), h2of(hv, 3), a1);
                }
                #pragma unroll 4
                for (int it = 16; it < 28; ++it) {
                    h8_t w  = wc[it * 256 + j8];
                    h8_t hv = *(const h8_t*)(hv_c + (it - 16) * 8);
                    a0 = FDOT2(h2of(w, 0), h2of(hv, 0), a0);
                    a1 = FDOT2(h2of(w, 1), h2of(hv, 1), a1);
                    a0 = FDOT2(h2of(w, 2), h2of(hv, 2), a0);
                    a1 = FDOT2(h2of(w, 3), h2of(hv, 3), a1);
                }
                #pragma unroll
                for (int it = 28; it < 32; ++it) {
                    h8_t w  = W1p[it * 256];
                    h8_t hv = *(const h8_t*)(hv_c + (it - 16) * 8);
                    a0 = FDOT2(h2of(w, 0), h2of(hv, 0), a0);
                    a1 = FDOT2(h2of(w, 1), h2of(hv, 1), a1);
                    a0 = FDOT2(h2of(w, 2), h2of(hv, 2), a0);
                    a1 = FDOT2(h2of(w, 3), h2of(hv, 3), a1);
                }
                red1[256 + j8] = a0 + a1;
            }
            LGKM0();
            if ((tid & 63) == 0) atomicAdd(&fl[AF], 1u);
            while (atomicAdd(&fl[AF], 0u) < 8u * tgt) __builtin_amdgcn_s_sleep(1);
            FENCE();
            // tanh/score partials: wave w covers j in [w*32, w*32+32), lane = t
            {
                const int w = tid >> 6, lane = tid & 63;
                float partial = 0.f;
                #pragma unroll 8
                for (int jj = 0; jj < 32; ++jj) {
                    const int j = w * 32 + jj;
                    float zj = red1[j] + red1[256 + j];
                    float v = (float)epl[j * 64 + lane] + zj;
                    partial += ftanh(v) * wa2s[j];
                }
                red2[w * 64 + lane] = partial;
            }
            LGKM0();
            if ((tid & 63) == 0) atomicAdd(&fl[CF], 1u);
            // waves 0-1: softmax + ytil + gates + update + state post
            if (tid < 128) {
                const int lane = tid & 63;
                while (atomicAdd(&fl[CF], 0u) < 8u * tgt) __builtin_amdgcn_s_sleep(1);
                FENCE();
                float s = 0.f;
                #pragma unroll
                for (int w2 = 0; w2 < 8; ++w2) s += red2[w2 * 64 + lane];
                float m = s;
                #pragma unroll
                for (int d = 32; d >= 1; d >>= 1) m = fmaxf(m, __shfl_xor(m, d));
                float e = __expf(s - m);
                float su = e;
                #pragma unroll
                for (int d = 32; d >= 1; d >>= 1) su += __shfl_xor(su, d);
                float a = e * __builtin_amdgcn_rcpf(su);
                if (tid < 64) attnw[lane] = a;
                float yp = a * encw[lane];
                #pragma unroll
                for (int d = 32; d >= 1; d >>= 1) yp += __shfl_xor(yp, d);
                const float ytil = yp + wfc_y * ys[step] + bfc0;
                while (atomicAdd(&fl[GF], 0u) < 8u * tgt) __builtin_amdgcn_s_sleep(1);
                FENCE();
                float gi = g2[tid]       + ytil * wii + bsi;
                float gf = g2[128 + tid] + ytil * wif + bsf;
                float gg = g2[256 + tid] + ytil * wig + bsg;
                float go = g2[384 + tid] + ytil * wio + bso;
                const int ih = h1 * 128 + tid;
                float co = hc[256 + ih];
                float cn = fsig(gf) * co + fsig(gi) * ftanh(gg);
                float hn = fsig(go) * ftanh(cn);
                hc[ih] = hn; hc[256 + ih] = cn;
                hcf16[ih] = (_Float16)hn; hcf16[256 + ih] = (_Float16)cn;
                LGKM0();
                if ((tid & 63) == 0) atomicAdd(&fl[UF], 1u);     // unblock next step
                // packed state post (buffer = step parity), early LLC flag
                unsigned* HXownP = HXbase + (((step & 1) * 128 + b) * 2 + h1) * 128;
                atomicExch(&HXownP[tid], pack_hc(hn, cn));
                asm volatile("s_waitcnt vmcnt(0)" ::: "memory");
                if ((tid & 63) == 0) atomicAdd(&fl[HF], 1u);
                if (tid == 0) {
                    while (atomicAdd(&fl[HF], 0u) < 2u * tgt) __builtin_amdgcn_s_sleep(1);
                    atomicExch(&FLGown[0], tgt);
                }
            }
        } else {
            // ===================== GROUP B =====================
            const int u2 = tid - 512;
            if (u2 < 128) {
                // waves 8-9: peer-state ingest
                if (step) {
                    while (atomicAdd(&FLGpeer[0], 0u) < (unsigned)step)
                        __builtin_amdgcn_s_sleep(1);
                    FENCE();
                    while (atomicAdd(&fl[UF], 0u) < 2u * (unsigned)step)
                        __builtin_amdgcn_s_sleep(1);
                    FENCE();
                    unsigned* HXpeerP = HXbase + ((((step - 1) & 1) * 128 + b) * 2 + (1 - h1)) * 128;
                    unsigned uu = atomicAdd(&HXpeerP[u2], 0u);
                    _Float16 hv16 = __builtin_bit_cast(_Float16, (unsigned short)(uu & 0xffffu));
                    _Float16 cv16 = __builtin_bit_cast(_Float16, (unsigned short)(uu >> 16));
                    const int ih = (1 - h1) * 128 + u2;
                    hcf16[ih] = hv16; hcf16[256 + ih] = cv16;
                    hc[ih] = (float)hv16;                        // epilogue f32 copy
                    LGKM0();
                    if ((u2 & 63) == 0) atomicAdd(&fl[SF], 1u);
                }
            }
            // all B waves: wait state complete (SF implies UF transitively)
            if (step) {
                while (atomicAdd(&fl[SF], 0u) < 2u * (unsigned)step)
                    __builtin_amdgcn_s_sleep(1);
                FENCE();
            }
            // P4: complete 256-k gate dot for q' = u2 (256 KB stream)
            float ga = 0.f, gb = 0.f;
            #pragma unroll 3
            for (int kk = 0; kk < 16; ++kk) {
                h8_t w0  = W4[kk * 1024];
                h8_t w1  = W4[kk * 1024 + 512];
                h8_t hv0 = *(const h8_t*)(hcf16 + kk * 8);
                h8_t hv1 = *(const h8_t*)(hcf16 + 128 + kk * 8);
                ga = FDOT2(h2of(w0, 0), h2of(hv0, 0), ga);
                gb = FDOT2(h2of(w1, 0), h2of(hv1, 0), gb);
                ga = FDOT2(h2of(w0, 1), h2of(hv0, 1), ga);
                gb = FDOT2(h2of(w1, 1), h2of(hv1, 1), gb);
                ga = FDOT2(h2of(w0, 2), h2of(hv0, 2), ga);
                gb = FDOT2(h2of(w1, 2), h2of(hv1, 2), gb);
                ga = FDOT2(h2of(w0, 3), h2of(hv0, 3), ga);
                gb = FDOT2(h2of(w1, 3), h2of(hv1, 3), gb);
            }
            g2[u2] = ga + gb;
            LGKM0();
            if ((u2 & 63) == 0) atomicAdd(&fl[GF], 1u);
        }
    }

    __syncthreads();                                   // join all waves
    // ---- final: read peer h for the epilogue (state_NSTEP in buffer 0) ----
    if (tid == 0) {
        while (atomicAdd(&FLGpeer[0], 0u) < (unsigned)NSTEP) { __builtin_amdgcn_s_sleep(1); }
    }
    __syncthreads();
    if (tid < 128) {
        unsigned* HXpeerF = HXbase + ((((NSTEP - 1) & 1) * 128 + b) * 2 + (1 - h1)) * 128;
        unsigned uu = atomicAdd(&HXpeerF[tid], 0u);
        _Float16 hv16 = __builtin_bit_cast(_Float16, (unsigned short)(uu & 0xffffu));
        hc[(1 - h1) * 128 + tid] = (float)hv16;
    }
    __syncthreads();

    // ---- epilogue (h1 == 0 only): final ctx from attnw, then out ----
    if (h1 == 0) {
        if (tid < 256) {
            float cv = 0.f;
            #pragma unroll 8
            for (int t = 0; t < TENC; ++t)
                cv += attnw[t] * encb[t * 256 + tid];
            red1[tid] = cv;
        }
        __syncthreads();
        if (tid < 128) {
            const int wvv = tid >> 6, lane = tid & 63;
            float partial = 0.f;
            #pragma unroll
            for (int qq = 0; qq < 8; ++qq) {
                const int e2 = qq * 64 + lane;
                float v = (e2 < 256) ? hc[e2] : red1[e2 - 256];
                partial += v * Wff[wvv * 512 + e2];
            }
            #pragma unroll
            for (int d = 32; d >= 1; d >>= 1) partial += __shfl_xor(partial, d);
            if (lane == 0) out[b * 2 + wvv] = partial + bff[wvv];
        }
    }
}

// ---------------------------------------------------------------------------
extern "C" void kernel_launch(void* const* d_in, const int* in_sizes, int n_in,
                              void* d_out, int out_size, void* d_ws, size_t ws_size,
                              hipStream_t stream) {
    const float* enc = (const float*)d_in[0];
    const float* yh  = (const float*)d_in[1];
    const float* Wa1 = (const float*)d_in[2];
    const float* ba1 = (const float*)d_in[3];
    const float* Wa2 = (const float*)d_in[4];
    // d_in[5] = b_a2 : softmax shift-invariant, unused
    const float* Wfc = (const float*)d_in[6];
    const float* bfc = (const float*)d_in[7];
    const float* Wih = (const float*)d_in[8];
    const float* Whh = (const float*)d_in[9];
    const float* bih = (const float*)d_in[10];
    const float* bhh = (const float*)d_in[11];
    const float* Wff = (const float*)d_in[12];
    const float* bff = (const float*)d_in[13];
    float* ws  = (float*)d_ws;
    float* out = (float*)d_out;

    hipLaunchKernelGGL(pack_weights, dim3(1792), dim3(256), 0, stream, Wa1, Whh, ws);
    hipLaunchKernelGGL(zero_flags, dim3(1), dim3(512), 0, stream, ws);
    hipLaunchKernelGGL(enc_proj_kernel, dim3(256), dim3(256), 0, stream, enc, ba1, ws);
    hipLaunchKernelGGL(decoder_main, dim3(256), dim3(1024), 0, stream,
                       enc, yh, Wa2, Wfc, bfc, Wih, bih, bhh, Wff, bff, ws, out);
}

// Round 17
// 397.962 us; speedup vs baseline: 1.1712x; 1.1712x over previous
//
#include <hip/hip_runtime.h>
#include <math.h>

// Problem constants
#define BATCH 128
#define TENC  64
#define NSTEP 63

// Workspace layout (FLOAT offsets)
#define OFF_WA1ET  0         // [256 k][256 j] f32 : W_a1[j][512+k]  (enc part, for enc_proj)
#define OFF_EPT    65536     // [128 b][256 j][64 t] f32
#define OFF_PKH    2162688   // fp16 region (half offsets within):
                             //   PK1n: [0,131072) = [hp<2][kc<8][seg<2][it<4][j7<128][m<8]
                             //         = Wa1[hp*128+j7][k], k = owner(seg,hp) slice, idx256=kc*32+it*8+m
                             //   PKG:  [131072,393216) = [h1<2][kk<16][kh<2][q'<512][m<8]
                             //         = Whh[q][k], q=(q'>>7)*256+h1*128+(q'&127), k=kh*128+kk*8+m
#define OFF_SX     2359296   // [128 b][2 half][64] f32    score-partial exchange
#define OFF_HX     2375680   // [128 b][2 half][128] u32   packed state exchange {h:f16 lo, c:f16 hi}
#define OFF_FLAGS  2408448   // [128 b][2 half][2] uint    (monotonic; 0=state, 1=scores)

typedef __attribute__((ext_vector_type(8))) _Float16 h8_t;
typedef __attribute__((ext_vector_type(2))) _Float16 h2_t;

#if defined(__has_builtin)
#if __has_builtin(__builtin_amdgcn_fdot2)
#define FDOT2(a, b, c) __builtin_amdgcn_fdot2((a), (b), (c), false)
#endif
#endif
#ifndef FDOT2
#define FDOT2(a, b, c) ((c) + (float)(a)[0] * (float)(b)[0] + (float)(a)[1] * (float)(b)[1])
#endif

__device__ __forceinline__ h2_t h2of(h8_t v, int i) {
    h2_t r = {v[2 * i], v[2 * i + 1]};
    return r;
}
__device__ __forceinline__ float ftanh(float x) {
    x = fminf(15.f, fmaxf(-15.f, x));
    float e = __expf(2.f * x);
    return (e - 1.f) * __builtin_amdgcn_rcpf(e + 1.f);
}
__device__ __forceinline__ float fsig(float x) {
    return __builtin_amdgcn_rcpf(1.f + __expf(-x));
}
__device__ __forceinline__ unsigned pack_hc(float h, float c) {
    unsigned short hu = __builtin_bit_cast(unsigned short, (_Float16)h);
    unsigned short cu = __builtin_bit_cast(unsigned short, (_Float16)c);
    return (unsigned)hu | ((unsigned)cu << 16);
}

// ---------------------------------------------------------------------------
// Pre-kernel A: pack weights (fp16 stream-ordered) + WA1ET (f32)
// ---------------------------------------------------------------------------
__global__ void pack_weights(const float* __restrict__ Wa1,
                             const float* __restrict__ Whh,
                             float* __restrict__ ws) {
    int idx = blockIdx.x * blockDim.x + threadIdx.x;
    _Float16* PKH = (_Float16*)(ws + OFF_PKH);
    if (idx < 131072) {
        // PK1n: j-split, full-k, own-k segment first then peer-k segment
        int m = idx & 7, j7 = (idx >> 3) & 127, it = (idx >> 10) & 3;
        int seg = (idx >> 12) & 1, kc = (idx >> 13) & 7, hp = (idx >> 16) & 1;
        int owner = seg ? (1 - hp) : hp;
        int idx256 = kc * 32 + it * 8 + m;
        int k = (idx256 < 128) ? owner * 128 + idx256
                               : 256 + owner * 128 + (idx256 - 128);
        int j = hp * 128 + j7;
        PKH[idx] = (_Float16)Wa1[j * 768 + k];
    } else if (idx < 393216) {
        int n = idx - 131072;
        int m = n & 7, qp = (n >> 3) & 511, kh = (n >> 12) & 1, kk = (n >> 13) & 15, h1 = n >> 17;
        int q = ((qp >> 7) << 8) + h1 * 128 + (qp & 127);
        int k = kh * 128 + kk * 8 + m;
        PKH[131072 + n] = (_Float16)Whh[q * 256 + k];
    } else if (idx < 458752) {
        int n = idx - 393216;
        int k = n >> 8, j = n & 255;
        ws[OFF_WA1ET + n] = Wa1[j * 768 + 512 + k];
    }
}

// Pre-kernel A2: zero the exchange flags (every launch, before decoder)
__global__ void zero_flags(float* __restrict__ ws) {
    unsigned* f = (unsigned*)(ws + OFF_FLAGS);
    f[threadIdx.x] = 0u;   // 512 = [128][2][2]
}

// ---------------------------------------------------------------------------
// Pre-kernel B: EPT[b][j][t] = b_a1[j] + sum_k enc[b][t][k] * W_a1[j][512+k]
// ---------------------------------------------------------------------------
__global__ void enc_proj_kernel(const float* __restrict__ enc,
                                const float* __restrict__ ba1,
                                float* __restrict__ ws) {
    __shared__ float smem[8448];
    const int b  = blockIdx.x >> 1;
    const int th = blockIdx.x & 1;
    const int t0 = th * 32;
    const int tid = threadIdx.x;

    const float* encb = enc + (b * TENC + t0) * 256;
    for (int c = 0; c < 32; ++c) smem[c * 256 + tid] = encb[c * 256 + tid];
    __syncthreads();

    const int w = tid >> 6, l = tid & 63;
    float acc[8][4];
    #pragma unroll
    for (int a = 0; a < 8; ++a)
        #pragma unroll
        for (int c = 0; c < 4; ++c) acc[a][c] = 0.f;

    const float4* WT = (const float4*)(ws + OFF_WA1ET);
    for (int k = 0; k < 256; ++k) {
        float4 wv = WT[k * 64 + l];
        #pragma unroll
        for (int tt = 0; tt < 8; ++tt) {
            float e = smem[(w * 8 + tt) * 256 + k];
            acc[tt][0] += e * wv.x; acc[tt][1] += e * wv.y;
            acc[tt][2] += e * wv.z; acc[tt][3] += e * wv.w;
        }
    }
    float4 bb = ((const float4*)ba1)[l];
    __syncthreads();
    #pragma unroll
    for (int tt = 0; tt < 8; ++tt) {
        smem[(4 * l + 0) * 33 + w * 8 + tt] = acc[tt][0] + bb.x;
        smem[(4 * l + 1) * 33 + w * 8 + tt] = acc[tt][1] + bb.y;
        smem[(4 * l + 2) * 33 + w * 8 + tt] = acc[tt][2] + bb.z;
        smem[(4 * l + 3) * 33 + w * 8 + tt] = acc[tt][3] + bb.w;
    }
    __syncthreads();
    float* EPT = ws + OFF_EPT + b * 16384;
    for (int c = 0; c < 32; ++c) {
        int i = c * 256 + tid;
        int j = i >> 5, t5 = i & 31;
        EPT[j * 64 + t0 + t5] = smem[j * 33 + t5];
    }
}

// ---------------------------------------------------------------------------
// Main kernel: 256 WGs = 2 per batch (round-14 structure, consolidated).
// WG h1 owns state slice [h1*128,+128) AND attention j-half [h1*128,+128).
//  - epl staged as f16 (16 KB)  [systematic, pair-identical quantization]
//  - W_hh LDS cache 7 kk chunks (112 KB): port 272 KB/step
//  - packed u32 state exchange; score-partial exchange hidden under P4 stream
// ---------------------------------------------------------------------------
__global__ __launch_bounds__(1024, 4) void decoder_main(
    const float* __restrict__ enc, const float* __restrict__ yhist,
    const float* __restrict__ Wa2,
    const float* __restrict__ Wfc, const float* __restrict__ bfc,
    const float* __restrict__ wih, const float* __restrict__ bih,
    const float* __restrict__ bhh,
    const float* __restrict__ Wff, const float* __restrict__ bff,
    float* __restrict__ ws, float* __restrict__ out) {

    __shared__ float hc[512];        // f32 state: h = [0,256), c = [256,512)
    __shared__ _Float16 hcf16[512] __attribute__((aligned(16)));
    __shared__ float z[128];
    __shared__ float red1[1024];
    __shared__ float red2[1024];
    __shared__ float g2[1024];
    __shared__ float attnw[64];
    __shared__ float encw[64];
    __shared__ float sownl[64];
    __shared__ float wa2s[128];
    __shared__ float ys[64];
    __shared__ h8_t  wc[7168] __attribute__((aligned(16)));      // 112 KB W_hh kk 0..7
    __shared__ _Float16 epl[8192] __attribute__((aligned(16)));  // EPT own j-half f16

    const int bid  = blockIdx.x;
    const int b    = bid & 127;
    const int h1   = bid >> 7;
    const int tid  = threadIdx.x;
    const int lane = tid & 63;
    const int wv   = tid >> 6;

    const _Float16* PKH = (const _Float16*)(ws + OFF_PKH);

    // ---- stage per-batch data into LDS once ----
    const float* EPTb = ws + OFF_EPT + b * 16384 + h1 * 8192;
    const float* encb = enc + b * 16384;
    #pragma unroll
    for (int i = 0; i < 8; ++i)
        epl[i * 1024 + tid] = (_Float16)EPTb[i * 1024 + tid];
    const h8_t* PKGown = (const h8_t*)(PKH + 131072) + h1 * 16384;
    #pragma unroll
    for (int kk = 0; kk < 7; ++kk) wc[kk * 1024 + tid] = PKGown[kk * 1024 + tid];
    if (tid < 512) { hc[tid] = 0.f; hcf16[tid] = (_Float16)0.f; }
    if (tid < 128) wa2s[tid] = Wa2[h1 * 128 + tid];
    if (tid < NSTEP) ys[tid] = yhist[b * NSTEP + tid];
    const float bfc0  = bfc[0];
    const float wfc_y = Wfc[256];
    float wii = 0.f, wif = 0.f, wig = 0.f, wio = 0.f;
    float bsi = 0.f, bsf = 0.f, bsg = 0.f, bso = 0.f;
    if (tid < 128) {
        const int q0 = h1 * 128 + tid;
        wii = wih[q0];       bsi = bih[q0]       + bhh[q0];
        wif = wih[256 + q0]; bsf = bih[256 + q0] + bhh[256 + q0];
        wig = wih[512 + q0]; bsg = bih[512 + q0] + bhh[512 + q0];
        wio = wih[768 + q0]; bso = bih[768 + q0] + bhh[768 + q0];
    }
    {   // encw[t] = enc[t]·Wfc[0:256]
        const int t = tid >> 4, cch = tid & 15;
        float p = 0.f;
        #pragma unroll
        for (int i = 0; i < 16; ++i)
            p += encb[t * 256 + cch * 16 + i] * Wfc[cch * 16 + i];
        red1[t * 16 + cch] = p;
    }
    __syncthreads();
    if (tid < 64) {
        float s = 0.f;
        #pragma unroll
        for (int c = 0; c < 16; ++c) s += red1[tid * 16 + c];
        encw[tid] = s;
    }
    __syncthreads();

    // P1 thread mapping: j7 = tid&127, kc = tid>>7
    const int kc = tid >> 7, j7 = tid & 127;
    const h8_t* W1 = (const h8_t*)PKH + h1 * 8192 + kc * 1024 + j7;
    const _Float16* hb_own  = hcf16 + ((kc < 4) ? h1 * 128 + kc * 32
                                                : 256 + h1 * 128 + (kc - 4) * 32);
    const _Float16* hb_peer = hcf16 + ((kc < 4) ? (1 - h1) * 128 + kc * 32
                                                : 256 + (1 - h1) * 128 + (kc - 4) * 32);
    // P4 mapping
    const int kh = tid >> 9, qp = tid & 511;
    const h8_t* W4 = PKGown + kh * 512 + qp;
    const _Float16* hgk = hcf16 + kh * 128;

    // exchange buffers / flags
    float*    SXown  = ws + OFF_SX + (b * 2 + h1) * 64;
    float*    SXpeer = ws + OFF_SX + (b * 2 + (1 - h1)) * 64;
    unsigned* HXown  = (unsigned*)(ws + OFF_HX) + (b * 2 + h1) * 128;
    unsigned* HXpeer = (unsigned*)(ws + OFF_HX) + (b * 2 + (1 - h1)) * 128;
    unsigned* FLGown  = (unsigned*)(ws + OFF_FLAGS) + (b * 2 + h1) * 2;
    unsigned* FLGpeer = (unsigned*)(ws + OFF_FLAGS) + (b * 2 + (1 - h1)) * 2;

    for (int step = 0; step < NSTEP; ++step) {
        const unsigned tgt = (unsigned)(step + 1);
        float a0 = 0.f, a1 = 0.f;
        // ---- A1: own-k segment (64 KB stream; covers peer-state arrival) ----
        #pragma unroll
        for (int it = 0; it < 4; ++it) {
            h8_t w  = W1[it * 128];
            h8_t hv = *(const h8_t*)(hb_own + it * 8);
            a0 = FDOT2(h2of(w, 0), h2of(hv, 0), a0);
            a1 = FDOT2(h2of(w, 1), h2of(hv, 1), a1);
            a0 = FDOT2(h2of(w, 2), h2of(hv, 2), a0);
            a1 = FDOT2(h2of(w, 3), h2of(hv, 3), a1);
        }
        if (tid == 0 && step > 0) {
            while (atomicAdd(&FLGpeer[0], 0u) < (unsigned)step) { __builtin_amdgcn_s_sleep(1); }
        }
        __syncthreads();                                 // B0: peer-state flag seen
        if (tid < 128 && step > 0) {                     // packed peer state -> LDS
            unsigned u = atomicAdd(&HXpeer[tid], 0u);
            _Float16 hv16 = __builtin_bit_cast(_Float16, (unsigned short)(u & 0xffffu));
            _Float16 cv16 = __builtin_bit_cast(_Float16, (unsigned short)(u >> 16));
            const int ih = (1 - h1) * 128 + tid;
            hcf16[ih] = hv16; hcf16[256 + ih] = cv16;
            hc[ih] = (float)hv16;                        // epilogue-only f32 copy
        }
        __syncthreads();                                 // B0': peer state in LDS
        // ---- A2: peer-k segment ----
        #pragma unroll
        for (int it = 0; it < 4; ++it) {
            h8_t w  = W1[512 + it * 128];
            h8_t hv = *(const h8_t*)(hb_peer + it * 8);
            a0 = FDOT2(h2of(w, 0), h2of(hv, 0), a0);
            a1 = FDOT2(h2of(w, 1), h2of(hv, 1), a1);
            a0 = FDOT2(h2of(w, 2), h2of(hv, 2), a0);
            a1 = FDOT2(h2of(w, 3), h2of(hv, 3), a1);
        }
        red1[kc * 128 + j7] = a0 + a1;
        __syncthreads();                                 // B1: red1 ready
        if (tid < 128) {                                 // z full-k for own j-half
            float s = red1[tid];
            #pragma unroll
            for (int c = 1; c < 8; ++c) s += red1[c * 128 + tid];
            z[tid] = s;
        }
        __syncthreads();                                 // B2: z ready

        // ---- C: score partials over own j-half (8 tanh/thread) ----
        {
            const int jc = tid >> 6;
            float partial = 0.f;
            #pragma unroll
            for (int jj = 0; jj < 8; ++jj) {
                const int j = jc * 8 + jj;
                float v = (float)epl[j * 64 + lane] + z[j];
                partial += ftanh(v) * wa2s[j];
            }
            red2[jc * 64 + lane] = partial;
        }
        __syncthreads();                                 // B3: red2 ready

        // ---- C2: wave0 posts score-partials; all waves run P4 (hides RTT) ----
        if (wv == 0) {
            float s = 0.f;
            #pragma unroll
            for (int w2 = 0; w2 < 16; ++w2) s += red2[w2 * 64 + lane];
            sownl[lane] = s;
            atomicExch(&SXown[lane], s);
            asm volatile("s_waitcnt vmcnt(0)" ::: "memory");
            if (lane == 0) atomicExch(&FLGown[1], tgt);  // score flag
        }
        float g0 = 0.f, g1 = 0.f;
        #pragma unroll
        for (int kk = 0; kk < 7; ++kk) {                 // cached in LDS (112 KB)
            h8_t w  = wc[kk * 1024 + tid];
            h8_t hv = *(const h8_t*)(hgk + kk * 8);
            g0 = FDOT2(h2of(w, 0), h2of(hv, 0), g0);
            g1 = FDOT2(h2of(w, 1), h2of(hv, 1), g1);
            g0 = FDOT2(h2of(w, 2), h2of(hv, 2), g0);
            g1 = FDOT2(h2of(w, 3), h2of(hv, 3), g1);
        }
        #pragma unroll 3
        for (int kk = 7; kk < 16; ++kk) {                // streamed from L2 (144 KB)
            h8_t w  = W4[kk * 1024];
            h8_t hv = *(const h8_t*)(hgk + kk * 8);
            g0 = FDOT2(h2of(w, 0), h2of(hv, 0), g0);
            g1 = FDOT2(h2of(w, 1), h2of(hv, 1), g1);
            g0 = FDOT2(h2of(w, 2), h2of(hv, 2), g0);
            g1 = FDOT2(h2of(w, 3), h2of(hv, 3), g1);
        }
        g2[tid] = g0 + g1;
        if (tid == 0) {
            while (atomicAdd(&FLGpeer[1], 0u) < tgt) { __builtin_amdgcn_s_sleep(1); }
        }
        __syncthreads();                                 // B4: g2 ready + peer scores posted

        // ---- D+H fused (tid<128): redundant softmax + ytil, gate finalize,
        //      own-slice state update + packed post ----
        if (tid < 128) {
            float sp = atomicAdd(&SXpeer[lane], 0.f);
            float s  = sownl[lane] + sp;                 // commutative pair sum
            float m = s;
            #pragma unroll
            for (int d = 32; d >= 1; d >>= 1) m = fmaxf(m, __shfl_xor(m, d));
            float e = __expf(s - m);
            float su = e;
            #pragma unroll
            for (int d = 32; d >= 1; d >>= 1) su += __shfl_xor(su, d);
            float a = e * __builtin_amdgcn_rcpf(su);
            if (wv == 0) attnw[lane] = a;
            float yp = a * encw[lane];
            #pragma unroll
            for (int d = 32; d >= 1; d >>= 1) yp += __shfl_xor(yp, d);
            const float ytil = yp + wfc_y * ys[step] + bfc0;

            float gi = g2[tid]       + g2[512 + tid] + ytil * wii + bsi;
            float gf = g2[128 + tid] + g2[640 + tid] + ytil * wif + bsf;
            float gg = g2[256 + tid] + g2[768 + tid] + ytil * wig + bsg;
            float go = g2[384 + tid] + g2[896 + tid] + ytil * wio + bso;
            const int ih = h1 * 128 + tid;
            float co = hc[256 + ih];
            float cn = fsig(gf) * co + fsig(gi) * ftanh(gg);
            float hn = fsig(go) * ftanh(cn);
            hc[ih] = hn; hc[256 + ih] = cn;
            hcf16[ih] = (_Float16)hn; hcf16[256 + ih] = (_Float16)cn;
            atomicExch(&HXown[tid], pack_hc(hn, cn));    // packed post
        }
        __syncthreads();                                 // B6: updated + posts drained
        if (tid == 0) atomicExch(&FLGown[0], tgt);       // state flag
    }

    // ---- final: read peer h for the epilogue ----
    if (tid == 0) {
        while (atomicAdd(&FLGpeer[0], 0u) < (unsigned)NSTEP) { __builtin_amdgcn_s_sleep(1); }
    }
    __syncthreads();
    if (tid < 128) {
        unsigned u = atomicAdd(&HXpeer[tid], 0u);
        _Float16 hv16 = __builtin_bit_cast(_Float16, (unsigned short)(u & 0xffffu));
        hc[(1 - h1) * 128 + tid] = (float)hv16;
    }
    __syncthreads();

    // ---- epilogue (h1 == 0 only): final ctx from attnw, then out ----
    if (h1 == 0) {
        if (tid < 256) {
            float cv = 0.f;
            #pragma unroll 8
            for (int t = 0; t < TENC; ++t)
                cv += attnw[t] * encb[t * 256 + tid];
            red1[tid] = cv;
        }
        __syncthreads();
        if (wv < 2) {
            float partial = 0.f;
            #pragma unroll
            for (int qq = 0; qq < 8; ++qq) {
                const int e2 = qq * 64 + lane;
                float v = (e2 < 256) ? hc[e2] : red1[e2 - 256];
                partial += v * Wff[wv * 512 + e2];
            }
            #pragma unroll
            for (int d = 32; d >= 1; d >>= 1) partial += __shfl_xor(partial, d);
            if (lane == 0) out[b * 2 + wv] = partial + bff[wv];
        }
    }
}

// ---------------------------------------------------------------------------
extern "C" void kernel_launch(void* const* d_in, const int* in_sizes, int n_in,
                              void* d_out, int out_size, void* d_ws, size_t ws_size,
                              hipStream_t stream) {
    const float* enc = (const float*)d_in[0];
    const float* yh  = (const float*)d_in[1];
    const float* Wa1 = (const float*)d_in[2];
    const float* ba1 = (const float*)d_in[3];
    const float* Wa2 = (const float*)d_in[4];
    // d_in[5] = b_a2 : softmax shift-invariant, unused
    const float* Wfc = (const float*)d_in[6];
    const float* bfc = (const float*)d_in[7];
    const float* Wih = (const float*)d_in[8];
    const float* Whh = (const float*)d_in[9];
    const float* bih = (const float*)d_in[10];
    const float* bhh = (const float*)d_in[11];
    const float* Wff = (const float*)d_in[12];
    const float* bff = (const float*)d_in[13];
    float* ws  = (float*)d_ws;
    float* out = (float*)d_out;

    hipLaunchKernelGGL(pack_weights, dim3(1792), dim3(256), 0, stream, Wa1, Whh, ws);
    hipLaunchKernelGGL(zero_flags, dim3(1), dim3(512), 0, stream, ws);
    hipLaunchKernelGGL(enc_proj_kernel, dim3(256), dim3(256), 0, stream, enc, ba1, ws);
    hipLaunchKernelGGL(decoder_main, dim3(256), dim3(1024), 0, stream,
                       enc, yh, Wa2, Wfc, bfc, Wih, bih, bhh, Wff, bff, ws, out);
}